// Round 14
// baseline (80.448 us; speedup 1.0000x reference)
//
#include <hip/hip_runtime.h>
#include <hip/hip_bf16.h>
#include <stdint.h>

#define Bn 8192
#define Dk 512
#define SCALE1 0x7F7F7F7F   // e8m0 127 (=1.0) in every byte: opsel-proof

typedef __attribute__((ext_vector_type(8))) int   int8v;
typedef __attribute__((ext_vector_type(4))) int   int4v;
typedef __attribute__((ext_vector_type(16))) float f32x16;

// branchless fp4 e2m1 encode of x*16 (RNE-style thresholds), sign+3-bit code.
__device__ __forceinline__ uint32_t enc4(float x) {
  const float a = __builtin_fabsf(x);
  const uint32_t c =
      a < 0.046875f ? (a < 0.015625f ? 0u : 1u)
    : a < 0.109375f ? (a < 0.078125f ? 2u : 3u)
    : a < 0.21875f  ? (a < 0.15625f  ? 4u : 5u)
    :                 (a < 0.3125f   ? 6u : 7u);
  return c | (x < 0.f ? 8u : 0u);
}

// ---------------------------------------------------------------------------
// Kernel 1: fp32 -> fp4 e2m1 (values x16), written in the fragment-direct
// layout: [256 groups of 32 rows][8 kt][2 h][32 r][16B]  (8 KB per group).
// A wave's MFMA fragment (32 rows x K=64) is then one contiguous 1 KB block.
// Exact fp32 row norms via LDS partials. Block = 32 rows x 512 cols.
// ---------------------------------------------------------------------------
__global__ __launch_bounds__(256) void prep_kernel(
    const float* __restrict__ T, const float* __restrict__ M,
    uint8_t* __restrict__ Tq, uint8_t* __restrict__ Mq,
    float* __restrict__ tn, float* __restrict__ mn)
{
  __shared__ float pn[8][33];
  const int b = blockIdx.x;            // 512 blocks: 256 text + 256 image
  const bool isM = b >= 256;
  const int pb = b & 255;              // 32-row group
  const int rbase = pb * 32;
  const float* __restrict__ src = isM ? M : T;
  float* __restrict__ nrm = isM ? mn : tn;

  const int t = threadIdx.x;
  const int kt = t >> 5;               // K-tile (64 floats)
  const int r = t & 31;                // row within group

  const float4* rowp = (const float4*)(src + (size_t)(rbase + r) * Dk) + kt * 16;
  float s = 0.f;
  uint32_t w[8];
  #pragma unroll
  for (int j = 0; j < 16; ++j) {
    const float4 v = rowp[j];
    s += v.x * v.x + v.y * v.y + v.z * v.z + v.w * v.w;
    const uint32_t quad = enc4(v.x) | (enc4(v.y) << 4) |
                          (enc4(v.z) << 8) | (enc4(v.w) << 12);
    if (j & 1) w[j >> 1] |= quad << 16; else w[j >> 1] = quad;
  }
  pn[kt][r] = s;

  uint8_t* dst = (isM ? Mq : Tq) + (size_t)pb * 8192 + kt * 1024 + r * 16;
  *(int4v*)dst         = *(const int4v*)&w[0];   // h = 0 (k 0..31)
  *(int4v*)(dst + 512) = *(const int4v*)&w[4];   // h = 1 (k 32..63)

  __syncthreads();
  if (t < 32) {
    float a = 0.f;
    #pragma unroll
    for (int k = 0; k < 8; ++k) a += pn[k][t];
    nrm[rbase + t] = a;
  }
}

// ---------------------------------------------------------------------------
// Kernel 2: 128x128-tile MX-fp4 GEMM, NO LDS STAGING: fragments loaded
// straight from the pre-transposed global layout (1 KB contiguous per wave
// per frag -> perfectly coalesced dwordx4; intra-block re-reads are L1-hits,
// 12 KB/step working set). 4 waves (2 tc x 2 ir), 64x64 wave tile, acc=64,
// ~124 regs -> 4 waves/SIMD -> 4 INDEPENDENT blocks/CU; no K-loop barriers,
// 2-buffer register pipeline, compiler-scheduled waits. LDS only for norms
// + 4 KB reduction. Fused atomic-free epilogue (R13 math, dot' = 256*dot).
// ---------------------------------------------------------------------------
__global__ __launch_bounds__(256, 4) void gemm_epi_kernel(
    const uint8_t* __restrict__ Tq, const uint8_t* __restrict__ Mq,
    const float* __restrict__ tn, const float* __restrict__ mn,
    const int* __restrict__ groups,
    float2* __restrict__ part)
{
  __shared__ float2 tg_s[128];      // (text norm, group bits)
  __shared__ float2 mg_s[128];      // (image norm, group bits)
  __shared__ float2 red[4][128];    // 4 KB reduction buffer

  const int tid = threadIdx.x;
  const int wave = tid >> 6;
  const int lane = tid & 63;
  const int l31 = lane & 31, h = lane >> 5;

  // XCD swizzle: 4096 blocks = 8 xcd x (8 by x 64 bx), by FAST within XCD
  const int bid = blockIdx.x;
  const int xcd = bid & 7, lidx = bid >> 3;
  const int by = xcd * 8 + (lidx & 7);   // 0..63 text panel (128 rows)
  const int bx = lidx >> 3;              // 0..63 image panel (128 rows)
  const int brow = by * 128;
  const int bcol = bx * 128;

  const int tc = wave & 1;     // text half: rows tc*64 .. +64
  const int ir = wave >> 1;    // image half: rows ir*64 .. +64

  if (tid < 128) {
    tg_s[tid] = make_float2(tn[brow + tid], __uint_as_float((unsigned)groups[brow + tid]));
  } else {
    const int t = tid - 128;
    mg_s[t] = make_float2(mn[bcol + t], __uint_as_float((unsigned)groups[bcol + t]));
  }

  // fragment base pointers: group index = row/32
  const uint8_t* Tf = Tq + (size_t)(by * 4) * 8192;   // 4 groups per 128-row panel
  const uint8_t* Mf = Mq + (size_t)(bx * 4) * 8192;
  const int loff = h * 512 + l31 * 16;

  f32x16 acc[2][2];
  #pragma unroll
  for (int it = 0; it < 2; ++it)
    #pragma unroll
    for (int jt = 0; jt < 2; ++jt)
      #pragma unroll
      for (int e = 0; e < 16; ++e)
        acc[it][jt][e] = 0.f;

  const int4v z4 = {0, 0, 0, 0};

#define LOADF(KT, TF, MF)                                                      \
  do {                                                                         \
    _Pragma("unroll")                                                          \
    for (int q = 0; q < 2; ++q) {                                              \
      TF[q] = *(const int4v*)(Tf + (2 * tc + q) * 8192 + (KT) * 1024 + loff);  \
      MF[q] = *(const int4v*)(Mf + (2 * ir + q) * 8192 + (KT) * 1024 + loff);  \
    }                                                                          \
  } while (0)

#define DOMM(TF, MF)                                                           \
  do {                                                                         \
    __builtin_amdgcn_s_setprio(1);                                             \
    _Pragma("unroll")                                                          \
    for (int it = 0; it < 2; ++it) {                                           \
      const int8v a8 = __builtin_shufflevector(MF[it], z4, 0, 1, 2, 3, 4, 5, 6, 7); \
      _Pragma("unroll")                                                        \
      for (int jt = 0; jt < 2; ++jt) {                                         \
        const int8v b8 = __builtin_shufflevector(TF[jt], z4, 0, 1, 2, 3, 4, 5, 6, 7); \
        acc[it][jt] = __builtin_amdgcn_mfma_scale_f32_32x32x64_f8f6f4(         \
            a8, b8, acc[it][jt], 4, 4, 0, SCALE1, 0, SCALE1);                  \
      }                                                                        \
    }                                                                          \
    __builtin_amdgcn_s_setprio(0);                                             \
  } while (0)

  int4v ta[2], ma_[2], tb[2], mb_[2];
  LOADF(0, ta, ma_);
  LOADF(1, tb, mb_);
  DOMM(ta, ma_); LOADF(2, ta, ma_);
  DOMM(tb, mb_); LOADF(3, tb, mb_);
  DOMM(ta, ma_); LOADF(4, ta, ma_);
  DOMM(tb, mb_); LOADF(5, tb, mb_);
  DOMM(ta, ma_); LOADF(6, ta, ma_);
  DOMM(tb, mb_); LOADF(7, tb, mb_);
  DOMM(ta, ma_);
  DOMM(tb, mb_);
#undef LOADF
#undef DOMM

  __syncthreads();   // tg_s/mg_s fill visible

  // ---- fused epilogue (no atomics) ----
  // acc[it][jt][reg] on lane (l31,h) = 256 * dot(image[bcol+ir*64+it*32+crow],
  //                                              text [brow+tc*64+jt*32+l31])
  // with crow = (reg&3) + 8*(reg>>2) + 4*h.
  float nv[2] = {0.f, 0.f}, tot[2] = {0.f, 0.f};
  const int tlA = tc * 64 + l31;          // jt = 0
  const int tlB = tlA + 32;               // jt = 1
  const float2 tgA = tg_s[tlA];
  const float2 tgB = tg_s[tlB];
  #pragma unroll
  for (int it = 0; it < 2; ++it) {
    #pragma unroll
    for (int reg = 0; reg < 16; ++reg) {
      const int crow = (reg & 3) + 8 * (reg >> 2) + 4 * h;
      const float2 mg = mg_s[ir * 64 + it * 32 + crow];
      const unsigned gm = __float_as_uint(mg.y);
      {
        const float sq = fmaxf(fmaf(acc[it][0][reg], -0.0078125f, tgA.x + mg.x), 0.f);
        const float sim = __builtin_amdgcn_exp2f(-1.4426950408889634f *
                                                 __builtin_amdgcn_sqrtf(sq));
        tot[0] += sim;
        if (__float_as_uint(tgA.y) == gm) nv[0] += sim;
      }
      {
        const float sq = fmaxf(fmaf(acc[it][1][reg], -0.0078125f, tgB.x + mg.x), 0.f);
        const float sim = __builtin_amdgcn_exp2f(-1.4426950408889634f *
                                                 __builtin_amdgcn_sqrtf(sq));
        tot[1] += sim;
        if (__float_as_uint(tgB.y) == gm) nv[1] += sim;
      }
    }
  }
  const int slot = ir * 2 + h;
  red[slot][tlA] = make_float2(nv[0], tot[0]);
  red[slot][tlB] = make_float2(nv[1], tot[1]);
  __syncthreads();
  if (tid < 128) {
    float n = 0.f, d = 0.f;
    #pragma unroll
    for (int s = 0; s < 4; ++s) {
      const float2 v = red[s][tid];
      n += v.x; d += v.y;
    }
    part[(size_t)bx * Bn + brow + tid] = make_float2(n, d);   // (num, total)
  }
}

// ---------------------------------------------------------------------------
// Kernel 3a: per-row sum over 64 image-panel partials; dv = tot - nv;
// loss term -> block sums. Kernel 3b: final reduce of 32 block sums.
// ---------------------------------------------------------------------------
__global__ __launch_bounds__(256) void finalize1_kernel(
    const float2* __restrict__ part, float* __restrict__ bsum)
{
  const int i = blockIdx.x * 256 + threadIdx.x;
  float nv = 0.f, tv = 0.f;
  #pragma unroll 8
  for (int p = 0; p < 64; ++p) {
    const float2 v = part[(size_t)p * Bn + i];
    nv += v.x; tv += v.y;
  }
  const float dv = tv - nv;
  float li = (nv > 0.f && dv > 0.f)
      ? (__builtin_amdgcn_logf(dv) - __builtin_amdgcn_logf(nv)) * 0.69314718055994531f
      : 0.f;
  #pragma unroll
  for (int off = 32; off >= 1; off >>= 1) li += __shfl_xor(li, off, 64);
  __shared__ float ws4[4];
  if ((threadIdx.x & 63) == 0) ws4[threadIdx.x >> 6] = li;
  __syncthreads();
  if (threadIdx.x == 0) bsum[blockIdx.x] = ws4[0] + ws4[1] + ws4[2] + ws4[3];
}

__global__ void finalize2_kernel(const float* __restrict__ bsum, float* __restrict__ out)
{
  float s = (threadIdx.x < 32) ? bsum[threadIdx.x] : 0.f;
  #pragma unroll
  for (int off = 32; off >= 1; off >>= 1) s += __shfl_xor(s, off, 64);
  if (threadIdx.x == 0) out[0] = s / (float)Bn;
}

// ---------------------------------------------------------------------------
extern "C" void kernel_launch(void* const* d_in, const int* in_sizes, int n_in,
                              void* d_out, int out_size, void* d_ws, size_t ws_size,
                              hipStream_t stream) {
  const float* T = (const float*)d_in[0];
  const float* M = (const float*)d_in[1];
  const int* groups = (const int*)d_in[2];

  char* ws = (char*)d_ws;
  uint8_t* Tq = (uint8_t*)ws;                                   // 2 MB fp4 text (frag layout)
  uint8_t* Mq = (uint8_t*)(ws + (size_t)256 * 8192);            // 2 MB fp4 image
  float* tn  = (float*)(ws + (size_t)512 * 8192);               // 32 KB
  float* mn  = tn + Bn;                                         // 32 KB
  float2* part = (float2*)(mn + Bn);                            // 4 MB (64 x 8192)
  float* bsum = (float*)(part + (size_t)64 * Bn);               // 128 B

  prep_kernel<<<512, 256, 0, stream>>>(T, M, Tq, Mq, tn, mn);
  gemm_epi_kernel<<<4096, 256, 0, stream>>>(Tq, Mq, tn, mn, groups, part);
  finalize1_kernel<<<Bn / 256, 256, 0, stream>>>(part, bsum);
  finalize2_kernel<<<1, 64, 0, stream>>>(bsum, (float*)d_out);
}

// Round 15
// 59.432 us; speedup vs baseline: 1.3536x; 1.3536x over previous
//
#include <hip/hip_runtime.h>
#include <hip/hip_bf16.h>
#include <stdint.h>

#define Bn 8192
#define Dk 512
#define SCALE1 0x7F7F7F7F   // e8m0 127 (=1.0) in every byte: opsel-proof

typedef __attribute__((ext_vector_type(8))) int   int8v;
typedef __attribute__((ext_vector_type(4))) int   int4v;
typedef __attribute__((ext_vector_type(16))) float f32x16;

// async global -> LDS, 16 bytes per lane (dest = wave-uniform base + lane*16)
__device__ __forceinline__ void gload_lds16(const uint8_t* g, const uint8_t* l) {
  __builtin_amdgcn_global_load_lds(
      (const __attribute__((address_space(1))) void*)g,
      (__attribute__((address_space(3))) void*)l,
      16, 0, 0);
}

// branchless fp4 e2m1 encode of x*16 (RNE-style thresholds), sign+3-bit code.
__device__ __forceinline__ uint32_t enc4(float x) {
  const float a = __builtin_fabsf(x);
  const uint32_t c =
      a < 0.046875f ? (a < 0.015625f ? 0u : 1u)
    : a < 0.109375f ? (a < 0.078125f ? 2u : 3u)
    : a < 0.21875f  ? (a < 0.15625f  ? 4u : 5u)
    :                 (a < 0.3125f   ? 6u : 7u);
  return c | (x < 0.f ? 8u : 0u);
}

// ---------------------------------------------------------------------------
// Kernel 1 (COALESCED): fp32 -> fp4 e2m1 (values x16) in R13's transposed
// panel layout: text [32 by][8 kt][8 g][2 h][32 r][16B], image [64 bx][8 kt]
// [4 g][2 h][32 r][16B]. Block = one 32-row group; wave = 8 octets; octet o
// owns row w*8+o and reads it in 128 B contiguous slices (lane ol -> float4
// i*8+ol) => every 64 B line consumed in ONE instruction (no amplification).
// Octet shfl-pack assembles the 16 B word at lane ol==0 (k ascending, LSB
// first = R13 byte order); 8 leaders/wave write 128 B contiguous.
// Exact fp32 row norms via in-register accumulate + octet shfl_xor reduce.
// ---------------------------------------------------------------------------
__global__ __launch_bounds__(256) void prep_kernel(
    const float* __restrict__ T, const float* __restrict__ M,
    uint8_t* __restrict__ Tq, uint8_t* __restrict__ Mq,
    float* __restrict__ tn, float* __restrict__ mn)
{
  const int b = blockIdx.x;            // 512 blocks: 256 text + 256 image
  const bool isM = b >= 256;
  const int pb = b & 255;              // 32-row group index
  const int rbase = pb * 32;
  const float* __restrict__ src = isM ? M : T;
  float* __restrict__ nrm = isM ? mn : tn;

  const int tid = threadIdx.x;
  const int w = tid >> 6;              // wave 0..3
  const int l = tid & 63;
  const int oct = l >> 3;              // octet 0..7
  const int ol = l & 7;                // lane within octet
  const int r = w * 8 + oct;           // local row 0..31

  const float4* rowp = (const float4*)(src + (size_t)(rbase + r) * Dk);

  uint8_t* pbase;                      // (kt,h)-invariant part of the address
  int ksz;
  if (!isM) {
    pbase = Tq + (size_t)(pb >> 3) * 65536 + (pb & 7) * 1024 + r * 16;
    ksz = 8192;
  } else {
    pbase = Mq + (size_t)(pb >> 2) * 32768 + (pb & 3) * 1024 + r * 16;
    ksz = 4096;
  }

  float nacc = 0.f;
  #pragma unroll
  for (int i = 0; i < 16; ++i) {       // i = 8-float4 slice of the row
    const float4 v = rowp[i * 8 + ol];
    nacc += v.x * v.x + v.y * v.y + v.z * v.z + v.w * v.w;
    const uint32_t us = enc4(v.x) | (enc4(v.y) << 4) |
                        (enc4(v.z) << 8) | (enc4(v.w) << 12);
    const uint32_t p01 = us | ((uint32_t)__shfl_down((int)us, 1, 64) << 16);
    const uint32_t p23 = (uint32_t)__shfl_down((int)p01, 2, 64);
    const uint32_t p45 = (uint32_t)__shfl_down((int)p01, 4, 64);
    const uint32_t p67 = (uint32_t)__shfl_down((int)p01, 6, 64);
    if (ol == 0) {
      const int4v wd = {(int)p01, (int)p23, (int)p45, (int)p67};
      *(int4v*)(pbase + (i >> 1) * ksz + (i & 1) * 512) = wd;
    }
  }

  // exact fp32 row norm: octet holds disjoint slices of row r
  nacc += __shfl_xor(nacc, 1, 64);
  nacc += __shfl_xor(nacc, 2, 64);
  nacc += __shfl_xor(nacc, 4, 64);
  if (ol == 0) nrm[rbase + r] = nacc;
}

// ---------------------------------------------------------------------------
// Kernel 2: R13 verbatim — 256x128-tile MX-fp4 GEMM (scale=1.0, fmt=4 E2M1),
// BK=64, ring-3, counted vmcnt(4), 8 waves (4 tc x 2 ir), 64x64 wave tile,
// 2 blocks/CU. Staging = linear panel copy; frag read = contiguous 1 KB per
// wave (zero-conflict). dot' = 256*dot -> sq = fma(acc, -2/256, tn+mn).
// ---------------------------------------------------------------------------
__global__ __launch_bounds__(512, 4) void gemm_epi_kernel(
    const uint8_t* __restrict__ Tq, const uint8_t* __restrict__ Mq,
    const float* __restrict__ tn, const float* __restrict__ mn,
    const int* __restrict__ groups,
    float2* __restrict__ part)
{
  extern __shared__ char smem[];
  uint8_t* As8 = (uint8_t*)smem;              // text: 3 bufs x 8 KB
  uint8_t* Bs8 = As8 + 3 * 8192;              // image: 3 bufs x 8 KB (2 copies)
  float2* tg_s = (float2*)(Bs8 + 3 * 8192);   // 256 (text norm, group bits)
  float2* mg_s = tg_s + 256;                  // 128 (image norm, group bits)

  const int tid = threadIdx.x;
  const int wave = tid >> 6;
  const int lane = tid & 63;
  const int l31 = lane & 31, h = lane >> 5;

  // XCD-compact swizzle, by FAST within XCD (R8/R12 reuse axis)
  const int bid = blockIdx.x;
  const int xcd = bid & 7, lidx = bid >> 3;
  const int by = xcd * 4 + (lidx & 3);   // 0..31 text panel (256 rows)
  const int bx = lidx >> 2;              // 0..63 image panel (128 rows)
  const int brow = by * 256;
  const int bcol = bx * 128;

  const int tc = wave & 3;     // text quarter: rows tc*64 .. +64
  const int ir = wave >> 2;    // image half:  rows ir*64 .. +64

  if (tid < 256) {
    tg_s[tid] = make_float2(tn[brow + tid], __uint_as_float((unsigned)groups[brow + tid]));
  } else if (tid < 384) {
    const int t = tid - 256;
    mg_s[t] = make_float2(mn[bcol + t], __uint_as_float((unsigned)groups[bcol + t]));
  }

  // staging: linear panel copy (source pre-transposed by prep)
  const uint8_t* Tpan = Tq + (size_t)by * 65536;
  const uint8_t* Mpan = Mq + (size_t)bx * 32768;
  const unsigned gT = (unsigned)tid * 16;            // text chunk (8 KB)
  const unsigned gM = (unsigned)(tid & 255) * 16;    // image chunk (4 KB, dup'd)
  const int ldsOff = tid * 16;

  auto stage = [&](int t, int buf) {
    gload_lds16(Tpan + (unsigned)t * 8192 + gT, As8 + buf * 8192 + ldsOff);
    gload_lds16(Mpan + (unsigned)t * 4096 + gM, Bs8 + buf * 8192 + ldsOff);
  };

  // fragment read offsets: one contiguous 1 KB block per wave per fragment
  int toffB[2], moffB[2];
  #pragma unroll
  for (int jt = 0; jt < 2; ++jt)
    toffB[jt] = (tc * 2 + jt) * 1024 + h * 512 + l31 * 16;
  #pragma unroll
  for (int it = 0; it < 2; ++it)
    moffB[it] = ir * 4096 + (ir * 2 + it) * 1024 + h * 512 + l31 * 16;

  f32x16 acc[2][2];
  #pragma unroll
  for (int it = 0; it < 2; ++it)
    #pragma unroll
    for (int jt = 0; jt < 2; ++jt)
      #pragma unroll
      for (int e = 0; e < 16; ++e)
        acc[it][jt][e] = 0.f;

  const int4v z4 = {0, 0, 0, 0};

  // prologue: tiles 0,1 staged; tile 0 resident before first reads
  stage(0, 0); stage(1, 1);
  asm volatile("s_waitcnt vmcnt(2)" ::: "memory");
  __builtin_amdgcn_s_barrier();
  int kt = 0;

#define STEP(BUF, DO_STAGE, VMC)                                               \
  do {                                                                         \
    __builtin_amdgcn_s_barrier();                                              \
    if (DO_STAGE) stage(kt + 2, ((BUF) + 2) % 3);                              \
    asm volatile("s_waitcnt vmcnt(" #VMC ")" ::: "memory");                    \
    int4v tf[2], mf[2];                                                        \
    _Pragma("unroll")                                                          \
    for (int jt = 0; jt < 2; ++jt)                                             \
      tf[jt] = *(const int4v*)(As8 + (BUF) * 8192 + toffB[jt]);                \
    _Pragma("unroll")                                                          \
    for (int it = 0; it < 2; ++it)                                             \
      mf[it] = *(const int4v*)(Bs8 + (BUF) * 8192 + moffB[it]);                \
    __builtin_amdgcn_s_setprio(1);                                             \
    _Pragma("unroll")                                                          \
    for (int it = 0; it < 2; ++it) {                                           \
      const int8v a8 = __builtin_shufflevector(mf[it], z4, 0, 1, 2, 3, 4, 5, 6, 7); \
      _Pragma("unroll")                                                        \
      for (int jt = 0; jt < 2; ++jt) {                                         \
        const int8v b8 = __builtin_shufflevector(tf[jt], z4, 0, 1, 2, 3, 4, 5, 6, 7); \
        acc[it][jt] = __builtin_amdgcn_mfma_scale_f32_32x32x64_f8f6f4(         \
            a8, b8, acc[it][jt], 4, 4, 0, SCALE1, 0, SCALE1);                  \
      }                                                                        \
    }                                                                          \
    __builtin_amdgcn_s_setprio(0);                                             \
    ++kt;                                                                      \
  } while (0)

  STEP(0, true,  4);   // kt=0: stages tile 2
  STEP(1, true,  4);   // kt=1: tile 3
  STEP(2, true,  4);   // kt=2: tile 4
  STEP(0, true,  4);   // kt=3: tile 5
  STEP(1, true,  4);   // kt=4: tile 6
  STEP(2, true,  4);   // kt=5: tile 7 (last)
  STEP(0, false, 2);   // kt=6: tiles 6,7 outstanding -> wait to 2
  STEP(1, false, 0);   // kt=7: drain
#undef STEP

  // ---- fused epilogue (no atomics) ----
  // acc[it][jt][reg] on lane (l31,h) = 256 * dot(image[bcol+ir*64+it*32+crow],
  //                                              text [brow+tc*64+jt*32+l31])
  // with crow = (reg&3) + 8*(reg>>2) + 4*h.
  float2* red = reinterpret_cast<float2*>(As8);   // 8 KB alias on buf0 (dead)

  float nv[2] = {0.f, 0.f}, tot[2] = {0.f, 0.f};
  const int tlA = tc * 64 + l31;          // jt = 0
  const int tlB = tlA + 32;               // jt = 1
  const float2 tgA = tg_s[tlA];
  const float2 tgB = tg_s[tlB];
  #pragma unroll
  for (int it = 0; it < 2; ++it) {
    #pragma unroll
    for (int reg = 0; reg < 16; ++reg) {
      const int crow = (reg & 3) + 8 * (reg >> 2) + 4 * h;
      const float2 mg = mg_s[ir * 64 + it * 32 + crow];
      const unsigned gm = __float_as_uint(mg.y);
      {
        const float sq = fmaxf(fmaf(acc[it][0][reg], -0.0078125f, tgA.x + mg.x), 0.f);
        const float sim = __builtin_amdgcn_exp2f(-1.4426950408889634f *
                                                 __builtin_amdgcn_sqrtf(sq));
        tot[0] += sim;
        if (__float_as_uint(tgA.y) == gm) nv[0] += sim;
      }
      {
        const float sq = fmaxf(fmaf(acc[it][1][reg], -0.0078125f, tgB.x + mg.x), 0.f);
        const float sim = __builtin_amdgcn_exp2f(-1.4426950408889634f *
                                                 __builtin_amdgcn_sqrtf(sq));
        tot[1] += sim;
        if (__float_as_uint(tgB.y) == gm) nv[1] += sim;
      }
    }
  }
  __syncthreads();   // all waves done with LDS tile bufs before red alias
  const int slot = ir * 2 + h;
  red[slot * 256 + tlA] = make_float2(nv[0], tot[0]);
  red[slot * 256 + tlB] = make_float2(nv[1], tot[1]);
  __syncthreads();
  if (tid < 256) {
    float n = 0.f, d = 0.f;
    #pragma unroll
    for (int s = 0; s < 4; ++s) {
      const float2 v = red[s * 256 + tid];
      n += v.x; d += v.y;
    }
    part[(size_t)bx * Bn + brow + tid] = make_float2(n, d);   // (num, total)
  }
}

// ---------------------------------------------------------------------------
// Kernel 3a: per-row sum over 64 image-panel partials; dv = tot - nv;
// loss term -> block sums. Kernel 3b: final reduce of 32 block sums.
// ---------------------------------------------------------------------------
__global__ __launch_bounds__(256) void finalize1_kernel(
    const float2* __restrict__ part, float* __restrict__ bsum)
{
  const int i = blockIdx.x * 256 + threadIdx.x;
  float nv = 0.f, tv = 0.f;
  #pragma unroll 8
  for (int p = 0; p < 64; ++p) {
    const float2 v = part[(size_t)p * Bn + i];
    nv += v.x; tv += v.y;
  }
  const float dv = tv - nv;
  float li = (nv > 0.f && dv > 0.f)
      ? (__builtin_amdgcn_logf(dv) - __builtin_amdgcn_logf(nv)) * 0.69314718055994531f
      : 0.f;
  #pragma unroll
  for (int off = 32; off >= 1; off >>= 1) li += __shfl_xor(li, off, 64);
  __shared__ float ws4[4];
  if ((threadIdx.x & 63) == 0) ws4[threadIdx.x >> 6] = li;
  __syncthreads();
  if (threadIdx.x == 0) bsum[blockIdx.x] = ws4[0] + ws4[1] + ws4[2] + ws4[3];
}

__global__ void finalize2_kernel(const float* __restrict__ bsum, float* __restrict__ out)
{
  float s = (threadIdx.x < 32) ? bsum[threadIdx.x] : 0.f;
  #pragma unroll
  for (int off = 32; off >= 1; off >>= 1) s += __shfl_xor(s, off, 64);
  if (threadIdx.x == 0) out[0] = s / (float)Bn;
}

// ---------------------------------------------------------------------------
extern "C" void kernel_launch(void* const* d_in, const int* in_sizes, int n_in,
                              void* d_out, int out_size, void* d_ws, size_t ws_size,
                              hipStream_t stream) {
  const float* T = (const float*)d_in[0];
  const float* M = (const float*)d_in[1];
  const int* groups = (const int*)d_in[2];

  char* ws = (char*)d_ws;
  uint8_t* Tq = (uint8_t*)ws;                                   // 2 MB fp4 text (transposed)
  uint8_t* Mq = (uint8_t*)(ws + (size_t)32 * 65536);            // 2 MB fp4 image (transposed)
  float* tn  = (float*)(ws + (size_t)64 * 65536);               // 32 KB
  float* mn  = tn + Bn;                                         // 32 KB
  float2* part = (float2*)(mn + Bn);                            // 4 MB (64 x 8192)
  float* bsum = (float*)(part + (size_t)64 * Bn);               // 128 B

  const int smem_bytes = 3 * 8192 + 3 * 8192 + 256 * 8 + 128 * 8;  // 52224 B
  hipFuncSetAttribute((const void*)gemm_epi_kernel,
                      hipFuncAttributeMaxDynamicSharedMemorySize, smem_bytes);

  prep_kernel<<<512, 256, 0, stream>>>(T, M, Tq, Mq, tn, mn);
  gemm_epi_kernel<<<2048, 512, smem_bytes, stream>>>(Tq, Mq, tn, mn, groups, part);
  finalize1_kernel<<<Bn / 256, 256, 0, stream>>>(part, bsum);
  finalize2_kernel<<<1, 64, 0, stream>>>(bsum, (float*)d_out);
}

// Round 16
// 57.572 us; speedup vs baseline: 1.3973x; 1.0323x over previous
//
#include <hip/hip_runtime.h>
#include <hip/hip_bf16.h>
#include <stdint.h>

#define Bn 8192
#define Dk 512
#define SCALE1 0x7F7F7F7F   // e8m0 127 (=1.0) in every byte: opsel-proof

typedef __attribute__((ext_vector_type(8))) int   int8v;
typedef __attribute__((ext_vector_type(4))) int   int4v;
typedef __attribute__((ext_vector_type(16))) float f32x16;

// async global -> LDS, 16 bytes per lane (dest = wave-uniform base + lane*16)
__device__ __forceinline__ void gload_lds16(const uint8_t* g, const uint8_t* l) {
  __builtin_amdgcn_global_load_lds(
      (const __attribute__((address_space(1))) void*)g,
      (__attribute__((address_space(3))) void*)l,
      16, 0, 0);
}

// branchless fp4 e2m1 encode of x*16 (RNE-style thresholds), sign+3-bit code.
__device__ __forceinline__ uint32_t enc4(float x) {
  const float a = __builtin_fabsf(x);
  const uint32_t c =
      a < 0.046875f ? (a < 0.015625f ? 0u : 1u)
    : a < 0.109375f ? (a < 0.078125f ? 2u : 3u)
    : a < 0.21875f  ? (a < 0.15625f  ? 4u : 5u)
    :                 (a < 0.3125f   ? 6u : 7u);
  return c | (x < 0.f ? 8u : 0u);
}

// ---------------------------------------------------------------------------
// Kernel 1 (coalesced, R15 pattern): fp32 -> fp4 e2m1 (values x16) in the
// UNIFIED 128-row-panel layout used by both operands:
//   [64 panels][8 kt][4 g][2 h][32 r][16B]   (32 KB per panel)
// Block = one 32-row group; octet o owns row w*8+o, reads 128 B contiguous
// slices; octet shfl-pack assembles the 16 B word at ol==0 (k ascending).
// Exact fp32 row norms via octet shfl_xor reduce.
// ---------------------------------------------------------------------------
__global__ __launch_bounds__(256) void prep_kernel(
    const float* __restrict__ T, const float* __restrict__ M,
    uint8_t* __restrict__ Tq, uint8_t* __restrict__ Mq,
    float* __restrict__ tn, float* __restrict__ mn)
{
  const int b = blockIdx.x;            // 512 blocks: 256 text + 256 image
  const bool isM = b >= 256;
  const int pb = b & 255;              // 32-row group index
  const int rbase = pb * 32;
  const float* __restrict__ src = isM ? M : T;
  float* __restrict__ nrm = isM ? mn : tn;
  uint8_t* __restrict__ q = isM ? Mq : Tq;

  const int tid = threadIdx.x;
  const int w = tid >> 6;              // wave 0..3
  const int l = tid & 63;
  const int oct = l >> 3;              // octet 0..7
  const int ol = l & 7;                // lane within octet
  const int r = w * 8 + oct;           // local row 0..31

  const float4* rowp = (const float4*)(src + (size_t)(rbase + r) * Dk);
  uint8_t* pbase = q + (size_t)(pb >> 2) * 32768 + (pb & 3) * 1024 + r * 16;

  float nacc = 0.f;
  #pragma unroll
  for (int i = 0; i < 16; ++i) {       // i = 8-float4 slice of the row
    const float4 v = rowp[i * 8 + ol];
    nacc += v.x * v.x + v.y * v.y + v.z * v.z + v.w * v.w;
    const uint32_t us = enc4(v.x) | (enc4(v.y) << 4) |
                        (enc4(v.z) << 8) | (enc4(v.w) << 12);
    const uint32_t p01 = us | ((uint32_t)__shfl_down((int)us, 1, 64) << 16);
    const uint32_t p23 = (uint32_t)__shfl_down((int)p01, 2, 64);
    const uint32_t p45 = (uint32_t)__shfl_down((int)p01, 4, 64);
    const uint32_t p67 = (uint32_t)__shfl_down((int)p01, 6, 64);
    if (ol == 0) {
      const int4v wd = {(int)p01, (int)p23, (int)p45, (int)p67};
      *(int4v*)(pbase + (i >> 1) * 4096 + (i & 1) * 512) = wd;
    }
  }

  nacc += __shfl_xor(nacc, 1, 64);
  nacc += __shfl_xor(nacc, 2, 64);
  nacc += __shfl_xor(nacc, 4, 64);
  if (ol == 0) nrm[rbase + r] = nacc;
}

// ---------------------------------------------------------------------------
// Kernel 2: 128x128-tile MX-fp4 GEMM (scale=1.0, fmt=4 E2M1), BK=64, ring-3,
// counted vmcnt, 256 threads = 4 waves (2 tc x 2 ir), 64x64 wave tile ->
// 4 INDEPENDENT blocks/CU (16 waves; barrier group = 4 waves, lockstep
// domain quartered vs R13). Staging = 1 gload_lds per operand per thread
// (4 KB tiles); frag reads contiguous 1 KB per wave (zero-conflict).
// dot' = 256*dot -> sq = fma(acc, -2/256, tn+mn). Atomic-free epilogue.
// ---------------------------------------------------------------------------
__global__ __launch_bounds__(256, 4) void gemm_epi_kernel(
    const uint8_t* __restrict__ Tq, const uint8_t* __restrict__ Mq,
    const float* __restrict__ tn, const float* __restrict__ mn,
    const int* __restrict__ groups,
    float2* __restrict__ part)
{
  extern __shared__ char smem[];
  uint8_t* As8 = (uint8_t*)smem;              // text: 3 bufs x 4 KB
  uint8_t* Bs8 = As8 + 3 * 4096;              // image: 3 bufs x 4 KB
  float2* tg_s = (float2*)(Bs8 + 3 * 4096);   // 128 (text norm, group bits)
  float2* mg_s = tg_s + 128;                  // 128 (image norm, group bits)

  const int tid = threadIdx.x;
  const int wave = tid >> 6;
  const int lane = tid & 63;
  const int l31 = lane & 31, h = lane >> 5;

  // XCD-compact swizzle, by FAST within XCD: 4096 blocks = 8 xcd x (8 by x 64 bx)
  const int bid = blockIdx.x;
  const int xcd = bid & 7, lidx = bid >> 3;
  const int by = xcd * 8 + (lidx & 7);   // 0..63 text panel (128 rows)
  const int bx = lidx >> 3;              // 0..63 image panel (128 rows)
  const int brow = by * 128;
  const int bcol = bx * 128;

  const int tc = wave & 1;     // text half: rows tc*64 .. +64
  const int ir = wave >> 1;    // image half: rows ir*64 .. +64

  if (tid < 128) {
    tg_s[tid] = make_float2(tn[brow + tid], __uint_as_float((unsigned)groups[brow + tid]));
  } else {
    const int t = tid - 128;
    mg_s[t] = make_float2(mn[bcol + t], __uint_as_float((unsigned)groups[bcol + t]));
  }

  // staging: linear panel copy (source pre-transposed by prep)
  const uint8_t* Tpan = Tq + (size_t)by * 32768;
  const uint8_t* Mpan = Mq + (size_t)bx * 32768;
  const unsigned gOff = (unsigned)tid * 16;
  const int ldsOff = tid * 16;

  auto stage = [&](int t, int buf) {
    gload_lds16(Tpan + (unsigned)t * 4096 + gOff, As8 + buf * 4096 + ldsOff);
    gload_lds16(Mpan + (unsigned)t * 4096 + gOff, Bs8 + buf * 4096 + ldsOff);
  };

  // fragment read offsets: one contiguous 1 KB block per wave per fragment
  int toffB[2], moffB[2];
  #pragma unroll
  for (int jt = 0; jt < 2; ++jt)
    toffB[jt] = (tc * 2 + jt) * 1024 + h * 512 + l31 * 16;
  #pragma unroll
  for (int it = 0; it < 2; ++it)
    moffB[it] = (ir * 2 + it) * 1024 + h * 512 + l31 * 16;

  f32x16 acc[2][2];
  #pragma unroll
  for (int it = 0; it < 2; ++it)
    #pragma unroll
    for (int jt = 0; jt < 2; ++jt)
      #pragma unroll
      for (int e = 0; e < 16; ++e)
        acc[it][jt][e] = 0.f;

  const int4v z4 = {0, 0, 0, 0};

  // prologue: tiles 0,1 staged; tile 0 resident before first reads
  stage(0, 0); stage(1, 1);
  asm volatile("s_waitcnt vmcnt(2)" ::: "memory");
  __builtin_amdgcn_s_barrier();
  int kt = 0;

#define STEP(BUF, DO_STAGE, VMC)                                               \
  do {                                                                         \
    __builtin_amdgcn_s_barrier();                                              \
    if (DO_STAGE) stage(kt + 2, ((BUF) + 2) % 3);                              \
    asm volatile("s_waitcnt vmcnt(" #VMC ")" ::: "memory");                    \
    int4v tf[2], mf[2];                                                        \
    _Pragma("unroll")                                                          \
    for (int jt = 0; jt < 2; ++jt)                                             \
      tf[jt] = *(const int4v*)(As8 + (BUF) * 4096 + toffB[jt]);                \
    _Pragma("unroll")                                                          \
    for (int it = 0; it < 2; ++it)                                             \
      mf[it] = *(const int4v*)(Bs8 + (BUF) * 4096 + moffB[it]);                \
    __builtin_amdgcn_s_setprio(1);                                             \
    _Pragma("unroll")                                                          \
    for (int it = 0; it < 2; ++it) {                                           \
      const int8v a8 = __builtin_shufflevector(mf[it], z4, 0, 1, 2, 3, 4, 5, 6, 7); \
      _Pragma("unroll")                                                        \
      for (int jt = 0; jt < 2; ++jt) {                                         \
        const int8v b8 = __builtin_shufflevector(tf[jt], z4, 0, 1, 2, 3, 4, 5, 6, 7); \
        acc[it][jt] = __builtin_amdgcn_mfma_scale_f32_32x32x64_f8f6f4(         \
            a8, b8, acc[it][jt], 4, 4, 0, SCALE1, 0, SCALE1);                  \
      }                                                                        \
    }                                                                          \
    __builtin_amdgcn_s_setprio(0);                                             \
    ++kt;                                                                      \
  } while (0)

  STEP(0, true,  4);   // kt=0: stages tile 2
  STEP(1, true,  4);   // kt=1: tile 3
  STEP(2, true,  4);   // kt=2: tile 4
  STEP(0, true,  4);   // kt=3: tile 5
  STEP(1, true,  4);   // kt=4: tile 6
  STEP(2, true,  4);   // kt=5: tile 7 (last)
  STEP(0, false, 2);   // kt=6: tile 7's 2 loads outstanding -> wait to 2
  STEP(1, false, 0);   // kt=7: drain
#undef STEP

  // ---- fused epilogue (no atomics) ----
  // acc[it][jt][reg] on lane (l31,h) = 256 * dot(image[bcol+ir*64+it*32+crow],
  //                                              text [brow+tc*64+jt*32+l31])
  // with crow = (reg&3) + 8*(reg>>2) + 4*h.
  float2* red = reinterpret_cast<float2*>(As8);   // 4 KB alias on buf0 (dead)

  float nv[2] = {0.f, 0.f}, tot[2] = {0.f, 0.f};
  const int tlA = tc * 64 + l31;          // jt = 0
  const int tlB = tlA + 32;               // jt = 1
  const float2 tgA = tg_s[tlA];
  const float2 tgB = tg_s[tlB];
  #pragma unroll
  for (int it = 0; it < 2; ++it) {
    #pragma unroll
    for (int reg = 0; reg < 16; ++reg) {
      const int crow = (reg & 3) + 8 * (reg >> 2) + 4 * h;
      const float2 mg = mg_s[ir * 64 + it * 32 + crow];
      const unsigned gm = __float_as_uint(mg.y);
      {
        const float sq = fmaxf(fmaf(acc[it][0][reg], -0.0078125f, tgA.x + mg.x), 0.f);
        const float sim = __builtin_amdgcn_exp2f(-1.4426950408889634f *
                                                 __builtin_amdgcn_sqrtf(sq));
        tot[0] += sim;
        if (__float_as_uint(tgA.y) == gm) nv[0] += sim;
      }
      {
        const float sq = fmaxf(fmaf(acc[it][1][reg], -0.0078125f, tgB.x + mg.x), 0.f);
        const float sim = __builtin_amdgcn_exp2f(-1.4426950408889634f *
                                                 __builtin_amdgcn_sqrtf(sq));
        tot[1] += sim;
        if (__float_as_uint(tgB.y) == gm) nv[1] += sim;
      }
    }
  }
  __syncthreads();   // all waves done with LDS tile bufs before red alias
  const int slot = ir * 2 + h;
  red[slot * 128 + tlA] = make_float2(nv[0], tot[0]);
  red[slot * 128 + tlB] = make_float2(nv[1], tot[1]);
  __syncthreads();
  if (tid < 128) {
    float n = 0.f, d = 0.f;
    #pragma unroll
    for (int s = 0; s < 4; ++s) {
      const float2 v = red[s * 128 + tid];
      n += v.x; d += v.y;
    }
    part[(size_t)bx * Bn + brow + tid] = make_float2(n, d);   // (num, total)
  }
}

// ---------------------------------------------------------------------------
// Kernel 3a: per-row sum over 64 image-panel partials; dv = tot - nv;
// loss term -> block sums. Kernel 3b: final reduce of 32 block sums.
// ---------------------------------------------------------------------------
__global__ __launch_bounds__(256) void finalize1_kernel(
    const float2* __restrict__ part, float* __restrict__ bsum)
{
  const int i = blockIdx.x * 256 + threadIdx.x;
  float nv = 0.f, tv = 0.f;
  #pragma unroll 8
  for (int p = 0; p < 64; ++p) {
    const float2 v = part[(size_t)p * Bn + i];
    nv += v.x; tv += v.y;
  }
  const float dv = tv - nv;
  float li = (nv > 0.f && dv > 0.f)
      ? (__builtin_amdgcn_logf(dv) - __builtin_amdgcn_logf(nv)) * 0.69314718055994531f
      : 0.f;
  #pragma unroll
  for (int off = 32; off >= 1; off >>= 1) li += __shfl_xor(li, off, 64);
  __shared__ float ws4[4];
  if ((threadIdx.x & 63) == 0) ws4[threadIdx.x >> 6] = li;
  __syncthreads();
  if (threadIdx.x == 0) bsum[blockIdx.x] = ws4[0] + ws4[1] + ws4[2] + ws4[3];
}

__global__ void finalize2_kernel(const float* __restrict__ bsum, float* __restrict__ out)
{
  float s = (threadIdx.x < 32) ? bsum[threadIdx.x] : 0.f;
  #pragma unroll
  for (int off = 32; off >= 1; off >>= 1) s += __shfl_xor(s, off, 64);
  if (threadIdx.x == 0) out[0] = s / (float)Bn;
}

// ---------------------------------------------------------------------------
extern "C" void kernel_launch(void* const* d_in, const int* in_sizes, int n_in,
                              void* d_out, int out_size, void* d_ws, size_t ws_size,
                              hipStream_t stream) {
  const float* T = (const float*)d_in[0];
  const float* M = (const float*)d_in[1];
  const int* groups = (const int*)d_in[2];

  char* ws = (char*)d_ws;
  uint8_t* Tq = (uint8_t*)ws;                                   // 2 MB fp4 text (panel layout)
  uint8_t* Mq = (uint8_t*)(ws + (size_t)64 * 32768);            // 2 MB fp4 image
  float* tn  = (float*)(ws + (size_t)128 * 32768);              // 32 KB
  float* mn  = tn + Bn;                                         // 32 KB
  float2* part = (float2*)(mn + Bn);                            // 4 MB (64 x 8192)
  float* bsum = (float*)(part + (size_t)64 * Bn);               // 128 B

  const int smem_bytes = 3 * 4096 + 3 * 4096 + 128 * 8 + 128 * 8;  // 26624 B
  hipFuncSetAttribute((const void*)gemm_epi_kernel,
                      hipFuncAttributeMaxDynamicSharedMemorySize, smem_bytes);

  prep_kernel<<<512, 256, 0, stream>>>(T, M, Tq, Mq, tn, mn);
  gemm_epi_kernel<<<4096, 256, smem_bytes, stream>>>(Tq, Mq, tn, mn, groups, part);
  finalize1_kernel<<<Bn / 256, 256, 0, stream>>>(part, bsum);
  finalize2_kernel<<<1, 64, 0, stream>>>(bsum, (float*)d_out);
}